// Round 9
// baseline (283.377 us; speedup 1.0000x reference)
//
#include <hip/hip_runtime.h>
#include <cstddef>

#define NN   50000
#define KNB  32
#define NBLK ((NN + 31) / 32)     // 1563 node-blocks of 32

typedef _Float16 h2    __attribute__((ext_vector_type(2)));
typedef _Float16 half8 __attribute__((ext_vector_type(8)));
typedef float    f4    __attribute__((ext_vector_type(4)));
typedef float    f8    __attribute__((ext_vector_type(8)));
typedef unsigned short ushort_t;

// ---------------- prep: W1^T / W2^T fp16 [N][K] + nb -> uint16 ------------
__global__ __launch_bounds__(256) void prep(const float* __restrict__ W1,
                                            const float* __restrict__ W2,
                                            _Float16* __restrict__ w1t,
                                            _Float16* __restrict__ w2t) {
  const int id = blockIdx.x * 256 + threadIdx.x;
  if (id < 128 * 512) {                     // w1t[n][k] = W1[k][n]
    const int n = id >> 9, k = id & 511;
    w1t[id] = (_Float16)W1[k * 128 + n];
  } else {
    const int id2 = id - 128 * 512;
    if (id2 < 64 * 128) {                   // w2t[n][k] = W2[k][n]
      const int n = id2 >> 7, k = id2 & 127;
      w2t[id2] = (_Float16)W2[k * 64 + n];
    }
  }
}

__global__ __launch_bounds__(256) void prepnb(const int* __restrict__ nb,
                                              ushort_t* __restrict__ nb16) {
  const int i = (blockIdx.x * 256 + threadIdx.x) * 4;
  if (i + 3 < NN * KNB) {
    const int4 v = *(const int4*)(nb + i);
    ushort4 u;
    u.x = (ushort_t)v.x; u.y = (ushort_t)v.y;
    u.z = (ushort_t)v.z; u.w = (ushort_t)v.w;
    *(ushort4*)(nb16 + i) = u;
  }
}

// ---------------- GEMM1: h1c[8][NN][16] = A[M,512]fp32 @ W1 + b1 ----------
// LDS-staged MFMA (R8 structure); epilogue writes the feature-chunked
// layout consumed by the chunk-resident median kernel.
__global__ __launch_bounds__(256) void gemm1_mfma(
    const float* __restrict__ A, const _Float16* __restrict__ Bt,
    const float* __restrict__ bias, _Float16* __restrict__ h1c, int M) {
  constexpr int K = 512, BM = 64, BK = 32;
  __shared__ _Float16 Ah[BM][40];     // 80B stride: <=2-way alias = free
  __shared__ _Float16 Bh[128][40];
  const int tid  = threadIdx.x;
  const int wave = tid >> 6;
  const int lane = tid & 63;
  const int mr   = lane & 15;
  const int kg   = lane >> 4;
  const int m0   = blockIdx.x * BM;

  const int srow = tid >> 2;          // 0..63
  const int sseg = (tid & 3) * 8;     // 0,8,16,24
  int aRow = m0 + srow;
  if (aRow >= M) aRow = M - 1;
  const float*    ap  = A  + (size_t)aRow * K + sseg;
  const _Float16* bp0 = Bt + (size_t)srow * K + sseg;
  const _Float16* bp1 = Bt + (size_t)(64 + srow) * K + sseg;

  f4 acc[8] = {};

  for (int k0 = 0; k0 < K; k0 += BK) {
    const f4 t0 = *(const f4*)ap;
    const f4 t1 = *(const f4*)(ap + 4);
    const half8 blo = *(const half8*)bp0;
    const half8 bhi = *(const half8*)bp1;
    const f8 av = {t0[0], t0[1], t0[2], t0[3], t1[0], t1[1], t1[2], t1[3]};
    *(half8*)&Ah[srow][sseg]      = __builtin_convertvector(av, half8);
    *(half8*)&Bh[srow][sseg]      = blo;
    *(half8*)&Bh[64 + srow][sseg] = bhi;
    __syncthreads();

    const half8 af = *(const half8*)&Ah[wave * 16 + mr][kg * 8];
    #pragma unroll
    for (int nt = 0; nt < 8; ++nt) {
      const half8 bf = *(const half8*)&Bh[nt * 16 + mr][kg * 8];
      acc[nt] = __builtin_amdgcn_mfma_f32_16x16x32_f16(af, bf, acc[nt], 0, 0, 0);
    }
    __syncthreads();
    ap += BK;
    bp0 += BK;
    bp1 += BK;
  }

  #pragma unroll
  for (int nt = 0; nt < 8; ++nt) {
    const float bv = bias[nt * 16 + mr];
    #pragma unroll
    for (int r = 0; r < 4; ++r) {
      const int row = m0 + wave * 16 + kg * 4 + r;
      if (row < M)
        h1c[((size_t)nt * NN + row) * 16 + mr] = (_Float16)(acc[nt][r] + bv);
    }
  }
}

// ---------------- GEMM2: h2c[4][NN][16] = med1c @ W2 + b2 -----------------
// A staged from the chunked med1c layout; output chunked for median2c.
__global__ __launch_bounds__(256) void gemm2_mfma(
    const _Float16* __restrict__ med1c, const _Float16* __restrict__ Bt,
    const float* __restrict__ bias, _Float16* __restrict__ h2c, int M) {
  constexpr int K = 128, BM = 64, BK = 32;
  __shared__ _Float16 Ah[BM][40];
  __shared__ _Float16 Bh[64][40];
  const int tid  = threadIdx.x;
  const int wave = tid >> 6;
  const int lane = tid & 63;
  const int mr   = lane & 15;
  const int kg   = lane >> 4;
  const int m0   = blockIdx.x * BM;

  const int srow = tid >> 2;
  const int sseg = (tid & 3) * 8;
  int aRow = m0 + srow;
  if (aRow >= M) aRow = M - 1;
  const _Float16* bp = Bt + (size_t)srow * K + sseg;

  f4 acc[4] = {};

  #pragma unroll
  for (int k0 = 0; k0 < K; k0 += BK) {
    const int kk = k0 + sseg;                 // multiple of 8
    const _Float16* ap =
        med1c + ((size_t)(kk >> 4) * NN + aRow) * 16 + (kk & 15);
    *(half8*)&Ah[srow][sseg] = *(const half8*)ap;
    *(half8*)&Bh[srow][sseg] = *(const half8*)bp;
    __syncthreads();

    const half8 af = *(const half8*)&Ah[wave * 16 + mr][kg * 8];
    #pragma unroll
    for (int nt = 0; nt < 4; ++nt) {
      const half8 bf = *(const half8*)&Bh[nt * 16 + mr][kg * 8];
      acc[nt] = __builtin_amdgcn_mfma_f32_16x16x32_f16(af, bf, acc[nt], 0, 0, 0);
    }
    __syncthreads();
    bp += BK;
  }

  #pragma unroll
  for (int nt = 0; nt < 4; ++nt) {
    const float bv = bias[nt * 16 + mr];
    #pragma unroll
    for (int r = 0; r < 4; ++r) {
      const int row = m0 + wave * 16 + kg * 4 + r;
      if (row < M)
        h2c[((size_t)nt * NN + row) * 16 + mr] = (_Float16)(acc[nt][r] + bv);
    }
  }
}

// ---------------- median machinery ----------------------------------------
__device__ __forceinline__ void ceh(h2& a, h2& b) {
  h2 lo = __builtin_elementwise_min(a, b);
  h2 hi = __builtin_elementwise_max(a, b);
  a = lo;
  b = hi;
}

// Batcher odd-even mergesort, 32 h2; only v[15] consumed -> DCE.
__device__ __forceinline__ void sort32h(h2 (&v)[32]) {
  #pragma unroll
  for (int p = 1; p < 32; p <<= 1) {
    #pragma unroll
    for (int k = p; k >= 1; k >>= 1) {
      #pragma unroll
      for (int j = k & (p - 1); j + k < 32; j += 2 * k) {
        #pragma unroll
        for (int i = 0; i < k; ++i) {
          if (i + j + k < 32) {
            if ((i + j) / (2 * p) == (i + j + k) / (2 * p)) {
              ceh(v[i + j], v[i + j + k]);
            }
          }
        }
      }
    }
  }
}

// Chunk-resident median layer 1 (+ReLU). Grid = 8 chunks (outer) x NBLK
// node-blocks (inner) so each chunk's 1.6 MB gather set is L2-resident per
// XCD during its phase. Wave = 8 nodes x 8 h2-lanes (16 feats). Block
// stages its 32 nodes' uint16 indices in LDS (2 KB).
__global__ __launch_bounds__(256) void median_relu1c(
    const h2* __restrict__ h1c, const ushort_t* __restrict__ nb16,
    h2* __restrict__ med1c) {
  const int c   = blockIdx.x / NBLK;
  const int nb0 = (blockIdx.x % NBLK) * 32;
  const int tid = threadIdx.x;
  __shared__ ushort_t sidx[32 * KNB];

  {
    const int gi = nb0 * KNB + tid * 4;
    ushort4 u = make_ushort4(0, 0, 0, 0);
    if (gi + 3 < NN * KNB) u = *(const ushort4*)(nb16 + gi);
    *(ushort4*)(sidx + tid * 4) = u;
  }
  __syncthreads();

  const int nloc = tid >> 3;              // 0..31 (node within block)
  const int f2   = tid & 7;               // h2 index within chunk
  const int node = nb0 + nloc;
  const h2* src = h1c + (size_t)c * NN * 8;

  h2 v[32];
  #pragma unroll
  for (int j = 0; j < KNB; ++j) {
    const int idx = sidx[nloc * KNB + j];
    v[j] = src[(size_t)idx * 8 + f2];
  }
  sort32h(v);
  const h2 z = (h2)((_Float16)0);
  if (node < NN)
    med1c[((size_t)c * NN + node) * 8 + f2] = __builtin_elementwise_max(v[15], z);
}

// Chunk-resident median layer 2; 4 chunks; fp32 output in standard layout.
__global__ __launch_bounds__(256) void median2c(
    const h2* __restrict__ h2c, const ushort_t* __restrict__ nb16,
    float2* __restrict__ O) {
  const int c   = blockIdx.x / NBLK;
  const int nb0 = (blockIdx.x % NBLK) * 32;
  const int tid = threadIdx.x;
  __shared__ ushort_t sidx[32 * KNB];

  {
    const int gi = nb0 * KNB + tid * 4;
    ushort4 u = make_ushort4(0, 0, 0, 0);
    if (gi + 3 < NN * KNB) u = *(const ushort4*)(nb16 + gi);
    *(ushort4*)(sidx + tid * 4) = u;
  }
  __syncthreads();

  const int nloc = tid >> 3;
  const int f2   = tid & 7;
  const int node = nb0 + nloc;
  const h2* src = h2c + (size_t)c * NN * 8;

  h2 v[32];
  #pragma unroll
  for (int j = 0; j < KNB; ++j) {
    const int idx = sidx[nloc * KNB + j];
    v[j] = src[(size_t)idx * 8 + f2];
  }
  sort32h(v);
  if (node < NN) {
    float2 o;
    o.x = (float)v[15][0];
    o.y = (float)v[15][1];
    O[(size_t)node * 32 + c * 8 + f2] = o;
  }
}

extern "C" void kernel_launch(void* const* d_in, const int* in_sizes, int n_in,
                              void* d_out, int out_size, void* d_ws, size_t ws_size,
                              hipStream_t stream) {
  const float* feat = (const float*)d_in[0];   // [50000,512]
  const float* W1   = (const float*)d_in[1];   // [512,128]
  const float* b1   = (const float*)d_in[2];   // [128]
  const float* W2   = (const float*)d_in[3];   // [128,64]
  const float* b2   = (const float*)d_in[4];   // [64]
  const int*   nb   = (const int*)d_in[5];     // [50000,32] (int32 on device)
  float* out = (float*)d_out;                  // [50000,64] fp32

  _Float16* h1c   = (_Float16*)d_ws;                // 12.8 MB  [8][NN][16]
  _Float16* med1c = h1c + (size_t)NN * 128;         // 12.8 MB  [8][NN][16]
  _Float16* w1t   = med1c + (size_t)NN * 128;       // 128 KB   [128][512]
  _Float16* w2t   = w1t + 128 * 512;                // 16 KB    [64][128]
  ushort_t* nb16  = (ushort_t*)(w2t + 64 * 128);    // 3.2 MB
  _Float16* h2c   = h1c;                            // reuse    [4][NN][16]

  prep<<<dim3(288), dim3(256), 0, stream>>>(W1, W2, w1t, w2t);
  prepnb<<<dim3((NN * KNB / 4 + 255) / 256), dim3(256), 0, stream>>>(nb, nb16);
  gemm1_mfma<<<dim3((NN + 63) / 64), dim3(256), 0, stream>>>(feat, w1t, b1, h1c, NN);
  median_relu1c<<<dim3(8 * NBLK), dim3(256), 0, stream>>>(
      (const h2*)h1c, nb16, (h2*)med1c);
  gemm2_mfma<<<dim3((NN + 63) / 64), dim3(256), 0, stream>>>(med1c, w2t, b2, h2c, NN);
  median2c<<<dim3(4 * NBLK), dim3(256), 0, stream>>>(
      (const h2*)h2c, nb16, (float2*)out);
}